// Round 1
// baseline (1328.254 us; speedup 1.0000x reference)
//
#include <hip/hip_runtime.h>

#define N_NODES 100000
#define N_EDGES 3200000
#define F_X 24
#define F_S 8
#define D_IN 32   // F_X + F_S
#define H_DIM 64
#define F_OUT 32

// ---------------------------------------------------------------------------
// Kernel 1: per-node MLP.  y[v] = relu(concat(x[v],scalars) @ W1 + b1) @ W2 + b2
// Weights staged in LDS (16.5 KB), fully unrolled register MACs.
// ---------------------------------------------------------------------------
__global__ __launch_bounds__(256) void node_mlp_kernel(
    const float* __restrict__ x,        // [N, F_X]
    const float* __restrict__ scalars,  // [F_S]
    const float* __restrict__ W1,       // [D_IN, H]
    const float* __restrict__ b1,       // [H]
    const float* __restrict__ W2,       // [H, F_OUT]
    const float* __restrict__ b2,       // [F_OUT]
    float* __restrict__ y)              // [N, F_OUT]
{
    __shared__ float sW1[D_IN * H_DIM];   // 8 KB
    __shared__ float sW2[H_DIM * F_OUT];  // 8 KB
    __shared__ float sb1[H_DIM];
    __shared__ float sb2[F_OUT];
    __shared__ float ss[F_S];

    const int tid = threadIdx.x;
    for (int i = tid; i < D_IN * H_DIM; i += 256) sW1[i] = W1[i];
    for (int i = tid; i < H_DIM * F_OUT; i += 256) sW2[i] = W2[i];
    if (tid < H_DIM)  sb1[tid] = b1[tid];
    if (tid < F_OUT)  sb2[tid] = b2[tid];
    if (tid < F_S)    ss[tid]  = scalars[tid];
    __syncthreads();

    const int v = blockIdx.x * 256 + tid;
    if (v >= N_NODES) return;

    // Load input row: 24 x-features (6x float4, rows are 96B = 16B aligned) + 8 scalars
    float h[D_IN];
    const float4* xr = reinterpret_cast<const float4*>(x + (size_t)v * F_X);
    #pragma unroll
    for (int i = 0; i < F_X / 4; ++i) {
        float4 t = xr[i];
        h[i * 4 + 0] = t.x; h[i * 4 + 1] = t.y;
        h[i * 4 + 2] = t.z; h[i * 4 + 3] = t.w;
    }
    #pragma unroll
    for (int i = 0; i < F_S; ++i) h[F_X + i] = ss[i];

    // Layer 1 + ReLU
    float hid[H_DIM];
    #pragma unroll
    for (int l = 0; l < H_DIM; ++l) hid[l] = sb1[l];
    #pragma unroll
    for (int k = 0; k < D_IN; ++k) {
        const float hk = h[k];
        #pragma unroll
        for (int l = 0; l < H_DIM; ++l)
            hid[l] = fmaf(hk, sW1[k * H_DIM + l], hid[l]);  // uniform LDS addr -> broadcast
    }
    #pragma unroll
    for (int l = 0; l < H_DIM; ++l) hid[l] = fmaxf(hid[l], 0.0f);

    // Layer 2
    float o[F_OUT];
    #pragma unroll
    for (int j = 0; j < F_OUT; ++j) o[j] = sb2[j];
    #pragma unroll
    for (int l = 0; l < H_DIM; ++l) {
        const float hl = hid[l];
        #pragma unroll
        for (int j = 0; j < F_OUT; ++j)
            o[j] = fmaf(hl, sW2[l * F_OUT + j], o[j]);
    }

    float4* yr = reinterpret_cast<float4*>(y + (size_t)v * F_OUT);
    #pragma unroll
    for (int j = 0; j < F_OUT / 4; ++j)
        yr[j] = make_float4(o[j * 4 + 0], o[j * 4 + 1], o[j * 4 + 2], o[j * 4 + 3]);
}

// ---------------------------------------------------------------------------
// Kernel 2: edge scatter.  out[dst] += y[src] for every edge.
// 8 lanes per edge; each lane handles one float4 chunk (4 atomics).
// Lane group's 8 float4 loads cover the edge's contiguous 128B row.
// ---------------------------------------------------------------------------
__global__ __launch_bounds__(256) void edge_scatter_kernel(
    const int* __restrict__ ei,   // [2, E] (row 0 = src, row 1 = dst)
    const float* __restrict__ y,  // [N, F_OUT]
    float* __restrict__ out)      // [N, F_OUT]
{
    const long long t = (long long)blockIdx.x * blockDim.x + threadIdx.x;
    const long long e = t >> 3;
    const int c = (int)(t & 7);
    if (e >= N_EDGES) return;

    const int src = ei[e];
    const int dst = ei[N_EDGES + e];

    const float4 v = reinterpret_cast<const float4*>(y + (size_t)src * F_OUT)[c];
    float* op = out + (size_t)dst * F_OUT + c * 4;
    atomicAdd(op + 0, v.x);
    atomicAdd(op + 1, v.y);
    atomicAdd(op + 2, v.z);
    atomicAdd(op + 3, v.w);
}

extern "C" void kernel_launch(void* const* d_in, const int* in_sizes, int n_in,
                              void* d_out, int out_size, void* d_ws, size_t ws_size,
                              hipStream_t stream) {
    const float* x       = (const float*)d_in[0];
    const float* scalars = (const float*)d_in[1];
    const int*   ei      = (const int*)d_in[2];
    const float* W1      = (const float*)d_in[3];
    const float* b1      = (const float*)d_in[4];
    const float* W2      = (const float*)d_in[5];
    const float* b2      = (const float*)d_in[6];
    float* out = (float*)d_out;
    float* y   = (float*)d_ws;   // [N_NODES, F_OUT] = 12.8 MB

    // 1) per-node MLP into workspace
    node_mlp_kernel<<<(N_NODES + 255) / 256, 256, 0, stream>>>(
        x, scalars, W1, b1, W2, b2, y);

    // 2) zero the output (poisoned by harness; not restored between replays)
    hipMemsetAsync(d_out, 0, (size_t)out_size * sizeof(float), stream);

    // 3) scatter-add over edges
    const long long threads = (long long)N_EDGES * 8;
    const int blocks = (int)((threads + 255) / 256);
    edge_scatter_kernel<<<blocks, 256, 0, stream>>>(ei, y, out);
}

// Round 2
// 722.453 us; speedup vs baseline: 1.8385x; 1.8385x over previous
//
#include <hip/hip_runtime.h>

#define N_NODES 100000
#define N_EDGES 3200000
#define F_X 24
#define F_S 8
#define D_IN 32   // F_X + F_S
#define H_DIM 64
#define F_OUT 32
#define SCAN_THREADS 1024

// ---------------------------------------------------------------------------
// Kernel 1: per-node MLP.  y[v] = relu(concat(x[v],scalars) @ W1 + b1) @ W2 + b2
// ---------------------------------------------------------------------------
__global__ __launch_bounds__(256) void node_mlp_kernel(
    const float* __restrict__ x,        // [N, F_X]
    const float* __restrict__ scalars,  // [F_S]
    const float* __restrict__ W1,       // [D_IN, H]
    const float* __restrict__ b1,       // [H]
    const float* __restrict__ W2,       // [H, F_OUT]
    const float* __restrict__ b2,       // [F_OUT]
    float* __restrict__ y)              // [N, F_OUT]
{
    __shared__ float sW1[D_IN * H_DIM];   // 8 KB
    __shared__ float sW2[H_DIM * F_OUT];  // 8 KB
    __shared__ float sb1[H_DIM];
    __shared__ float sb2[F_OUT];
    __shared__ float ss[F_S];

    const int tid = threadIdx.x;
    for (int i = tid; i < D_IN * H_DIM; i += 256) sW1[i] = W1[i];
    for (int i = tid; i < H_DIM * F_OUT; i += 256) sW2[i] = W2[i];
    if (tid < H_DIM)  sb1[tid] = b1[tid];
    if (tid < F_OUT)  sb2[tid] = b2[tid];
    if (tid < F_S)    ss[tid]  = scalars[tid];
    __syncthreads();

    const int v = blockIdx.x * 256 + tid;
    if (v >= N_NODES) return;

    float h[D_IN];
    const float4* xr = reinterpret_cast<const float4*>(x + (size_t)v * F_X);
    #pragma unroll
    for (int i = 0; i < F_X / 4; ++i) {
        float4 t = xr[i];
        h[i * 4 + 0] = t.x; h[i * 4 + 1] = t.y;
        h[i * 4 + 2] = t.z; h[i * 4 + 3] = t.w;
    }
    #pragma unroll
    for (int i = 0; i < F_S; ++i) h[F_X + i] = ss[i];

    float hid[H_DIM];
    #pragma unroll
    for (int l = 0; l < H_DIM; ++l) hid[l] = sb1[l];
    #pragma unroll
    for (int k = 0; k < D_IN; ++k) {
        const float hk = h[k];
        #pragma unroll
        for (int l = 0; l < H_DIM; ++l)
            hid[l] = fmaf(hk, sW1[k * H_DIM + l], hid[l]);
    }
    #pragma unroll
    for (int l = 0; l < H_DIM; ++l) hid[l] = fmaxf(hid[l], 0.0f);

    float o[F_OUT];
    #pragma unroll
    for (int j = 0; j < F_OUT; ++j) o[j] = sb2[j];
    #pragma unroll
    for (int l = 0; l < H_DIM; ++l) {
        const float hl = hid[l];
        #pragma unroll
        for (int j = 0; j < F_OUT; ++j)
            o[j] = fmaf(hl, sW2[l * F_OUT + j], o[j]);
    }

    float4* yr = reinterpret_cast<float4*>(y + (size_t)v * F_OUT);
    #pragma unroll
    for (int j = 0; j < F_OUT / 4; ++j)
        yr[j] = make_float4(o[j * 4 + 0], o[j * 4 + 1], o[j * 4 + 2], o[j * 4 + 3]);
}

// ---------------------------------------------------------------------------
// Kernel 2: degree histogram over destinations (int atomics).
// ---------------------------------------------------------------------------
__global__ __launch_bounds__(256) void hist_kernel(
    const int* __restrict__ ei, int* __restrict__ deg)
{
    const int e = blockIdx.x * 256 + threadIdx.x;
    if (e < N_EDGES) atomicAdd(&deg[ei[N_EDGES + e]], 1);
}

// ---------------------------------------------------------------------------
// Kernel 3: single-block exclusive scan of degrees -> offsets (and cursor copy).
// ---------------------------------------------------------------------------
__global__ __launch_bounds__(SCAN_THREADS) void scan_kernel(
    const int* __restrict__ deg, int* __restrict__ offsets, int* __restrict__ cursor)
{
    __shared__ int part[SCAN_THREADS];
    const int tid = threadIdx.x;
    const int chunk = (N_NODES + SCAN_THREADS - 1) / SCAN_THREADS;  // 98
    const int begin = tid * chunk;
    const int end = min(begin + chunk, N_NODES);

    int s = 0;
    for (int i = begin; i < end; ++i) s += deg[i];
    part[tid] = s;
    __syncthreads();

    // Hillis-Steele inclusive scan over the 1024 partials
    for (int off = 1; off < SCAN_THREADS; off <<= 1) {
        const int mine = part[tid];
        const int add = (tid >= off) ? part[tid - off] : 0;
        __syncthreads();
        part[tid] = mine + add;
        __syncthreads();
    }

    int run = (tid == 0) ? 0 : part[tid - 1];  // exclusive base
    for (int i = begin; i < end; ++i) {
        offsets[i] = run;
        cursor[i]  = run;
        run += deg[i];
    }
    if (tid == SCAN_THREADS - 1) offsets[N_NODES] = run;  // == N_EDGES
}

// ---------------------------------------------------------------------------
// Kernel 4: CSR fill — place each edge's src id into its dst's segment.
// ---------------------------------------------------------------------------
__global__ __launch_bounds__(256) void fill_kernel(
    const int* __restrict__ ei, int* __restrict__ cursor, int* __restrict__ csr_src)
{
    const int e = blockIdx.x * 256 + threadIdx.x;
    if (e < N_EDGES) {
        const int src = ei[e];
        const int dst = ei[N_EDGES + e];
        const int pos = atomicAdd(&cursor[dst], 1);
        csr_src[pos] = src;
    }
}

// ---------------------------------------------------------------------------
// Kernel 5: gather-sum. 8 lanes per node; lane c owns float4 chunk c.
// No atomics; writes every output element (no memset needed).
// ---------------------------------------------------------------------------
__global__ __launch_bounds__(256) void gather_kernel(
    const int* __restrict__ offsets, const int* __restrict__ csr_src,
    const float* __restrict__ y, float* __restrict__ out)
{
    const int t = blockIdx.x * 256 + threadIdx.x;
    const int v = t >> 3;
    const int c = t & 7;
    if (v >= N_NODES) return;

    const int beg = offsets[v];
    const int end = offsets[v + 1];

    float4 acc = make_float4(0.f, 0.f, 0.f, 0.f);
    for (int i = beg; i < end; ++i) {
        const int src = csr_src[i];  // same addr across the 8-lane group -> broadcast
        const float4 val = reinterpret_cast<const float4*>(y + (size_t)src * F_OUT)[c];
        acc.x += val.x; acc.y += val.y; acc.z += val.z; acc.w += val.w;
    }
    reinterpret_cast<float4*>(out + (size_t)v * F_OUT)[c] = acc;
}

extern "C" void kernel_launch(void* const* d_in, const int* in_sizes, int n_in,
                              void* d_out, int out_size, void* d_ws, size_t ws_size,
                              hipStream_t stream) {
    const float* x       = (const float*)d_in[0];
    const float* scalars = (const float*)d_in[1];
    const int*   ei      = (const int*)d_in[2];
    const float* W1      = (const float*)d_in[3];
    const float* b1      = (const float*)d_in[4];
    const float* W2      = (const float*)d_in[5];
    const float* b2      = (const float*)d_in[6];
    float* out = (float*)d_out;

    // Workspace layout (26.8 MB total)
    char* ws = (char*)d_ws;
    float* y       = (float*)ws;                         // 12,800,000 B
    int*   deg     = (int*)(ws + 12800000);              //    400,000 B
    int*   offsets = (int*)(ws + 13200000);              //    400,004 B
    int*   cursor  = (int*)(ws + 13600004);              //    400,000 B
    int*   csr_src = (int*)(ws + 14000004);              // 12,800,000 B

    // 1) per-node MLP into workspace
    node_mlp_kernel<<<(N_NODES + 255) / 256, 256, 0, stream>>>(
        x, scalars, W1, b1, W2, b2, y);

    // 2) zero degree histogram, then count
    hipMemsetAsync(deg, 0, (size_t)N_NODES * sizeof(int), stream);
    hist_kernel<<<(N_EDGES + 255) / 256, 256, 0, stream>>>(ei, deg);

    // 3) exclusive scan -> offsets, cursor
    scan_kernel<<<1, SCAN_THREADS, 0, stream>>>(deg, offsets, cursor);

    // 4) CSR fill
    fill_kernel<<<(N_EDGES + 255) / 256, 256, 0, stream>>>(ei, cursor, csr_src);

    // 5) gather-sum into output (writes all elements; no memset of d_out)
    const int gthreads = N_NODES * 8;
    gather_kernel<<<(gthreads + 255) / 256, 256, 0, stream>>>(offsets, csr_src, y, out);
}

// Round 3
// 371.728 us; speedup vs baseline: 3.5732x; 1.9435x over previous
//
#include <hip/hip_runtime.h>

#define N_NODES 100000
#define N_EDGES 3200000
#define F_X 24
#define F_S 8
#define D_IN 32   // F_X + F_S
#define H_DIM 64
#define F_OUT 32

#define NBIN 8
#define BIN_SIZE 12500                       // N_NODES / NBIN
#define FILL_BLOCKS 8192
#define FILL_SLOTS ((FILL_BLOCKS / NBIN) * 256)   // 262144 slots per bin

// float -> bf16 (round-to-nearest-even), returns low 16 bits
__device__ __forceinline__ unsigned bf16_rne(float f) {
    unsigned u = __float_as_uint(f);
    return (u + 0x7fffu + ((u >> 16) & 1u)) >> 16;
}

// ---------------------------------------------------------------------------
// Kernel 1: per-node MLP -> bf16 y table ([N_NODES, 32] bf16 = 16 uints/row)
// ---------------------------------------------------------------------------
__global__ __launch_bounds__(256) void node_mlp_kernel(
    const float* __restrict__ x, const float* __restrict__ scalars,
    const float* __restrict__ W1, const float* __restrict__ b1,
    const float* __restrict__ W2, const float* __restrict__ b2,
    unsigned* __restrict__ y)
{
    __shared__ float sW1[D_IN * H_DIM];
    __shared__ float sW2[H_DIM * F_OUT];
    __shared__ float sb1[H_DIM];
    __shared__ float sb2[F_OUT];
    __shared__ float ss[F_S];

    const int tid = threadIdx.x;
    for (int i = tid; i < D_IN * H_DIM; i += 256) sW1[i] = W1[i];
    for (int i = tid; i < H_DIM * F_OUT; i += 256) sW2[i] = W2[i];
    if (tid < H_DIM)  sb1[tid] = b1[tid];
    if (tid < F_OUT)  sb2[tid] = b2[tid];
    if (tid < F_S)    ss[tid]  = scalars[tid];
    __syncthreads();

    const int v = blockIdx.x * 256 + tid;
    if (v >= N_NODES) return;

    float h[D_IN];
    const float4* xr = reinterpret_cast<const float4*>(x + (size_t)v * F_X);
    #pragma unroll
    for (int i = 0; i < F_X / 4; ++i) {
        float4 t = xr[i];
        h[i * 4 + 0] = t.x; h[i * 4 + 1] = t.y;
        h[i * 4 + 2] = t.z; h[i * 4 + 3] = t.w;
    }
    #pragma unroll
    for (int i = 0; i < F_S; ++i) h[F_X + i] = ss[i];

    float hid[H_DIM];
    #pragma unroll
    for (int l = 0; l < H_DIM; ++l) hid[l] = sb1[l];
    #pragma unroll
    for (int k = 0; k < D_IN; ++k) {
        const float hk = h[k];
        #pragma unroll
        for (int l = 0; l < H_DIM; ++l)
            hid[l] = fmaf(hk, sW1[k * H_DIM + l], hid[l]);
    }
    #pragma unroll
    for (int l = 0; l < H_DIM; ++l) hid[l] = fmaxf(hid[l], 0.0f);

    float o[F_OUT];
    #pragma unroll
    for (int j = 0; j < F_OUT; ++j) o[j] = sb2[j];
    #pragma unroll
    for (int l = 0; l < H_DIM; ++l) {
        const float hl = hid[l];
        #pragma unroll
        for (int j = 0; j < F_OUT; ++j)
            o[j] = fmaf(hl, sW2[l * F_OUT + j], o[j]);
    }

    // pack 32 f32 -> 16 uints (bf16 pairs: elem 2k low, 2k+1 high)
    unsigned pk[16];
    #pragma unroll
    for (int k = 0; k < 16; ++k)
        pk[k] = bf16_rne(o[2 * k]) | (bf16_rne(o[2 * k + 1]) << 16);
    uint4* yr = reinterpret_cast<uint4*>(y + (size_t)v * 16);
    #pragma unroll
    for (int q = 0; q < 4; ++q)
        yr[q] = make_uint4(pk[q * 4], pk[q * 4 + 1], pk[q * 4 + 2], pk[q * 4 + 3]);
}

// ---------------------------------------------------------------------------
// Kernel 2: degree histogram (4 edges/thread, no-return int atomics)
// ---------------------------------------------------------------------------
__global__ __launch_bounds__(256) void hist_kernel(
    const int* __restrict__ ei, int* __restrict__ deg)
{
    const int t = blockIdx.x * 256 + threadIdx.x;   // 800,000 threads exactly
    #pragma unroll
    for (int k = 0; k < 4; ++k) {
        const int e = t + k * 800000;
        if (e < N_EDGES) atomicAdd(&deg[ei[N_EDGES + e]], 1);
    }
}

// ---------------------------------------------------------------------------
// Kernel 3a: per-block (1024-node) degree sums
// ---------------------------------------------------------------------------
__global__ __launch_bounds__(256) void scan_blocksum_kernel(
    const int* __restrict__ deg, int* __restrict__ bsum)
{
    __shared__ int red[256];
    const int t = threadIdx.x;
    const int base = blockIdx.x * 1024 + t * 4;
    int s = 0;
    if (base + 3 < N_NODES) {
        const int4 d = *reinterpret_cast<const int4*>(deg + base);
        s = d.x + d.y + d.z + d.w;
    } else {
        for (int k = 0; k < 4; ++k)
            if (base + k < N_NODES) s += deg[base + k];
    }
    red[t] = s;
    __syncthreads();
    for (int off = 128; off > 0; off >>= 1) {
        if (t < off) red[t] += red[t + off];
        __syncthreads();
    }
    if (t == 0) bsum[blockIdx.x] = red[0];
}

// ---------------------------------------------------------------------------
// Kernel 3b: one-wave exclusive scan of the 98 block sums
// ---------------------------------------------------------------------------
__global__ __launch_bounds__(64) void scan_top_kernel(
    const int* __restrict__ bsum, int* __restrict__ bbase, int* __restrict__ offsets,
    int nblk)
{
    const int l = threadIdx.x;
    int v0 = (l < nblk) ? bsum[l] : 0;
    int v1 = (l + 64 < nblk) ? bsum[l + 64] : 0;
    int a = v0;
    #pragma unroll
    for (int off = 1; off < 64; off <<= 1) {
        int u = __shfl_up(a, off, 64);
        if (l >= off) a += u;
    }
    const int tot0 = __shfl(a, 63, 64);
    int b = v1;
    #pragma unroll
    for (int off = 1; off < 64; off <<= 1) {
        int u = __shfl_up(b, off, 64);
        if (l >= off) b += u;
    }
    const int tot1 = __shfl(b, 63, 64);
    if (l < nblk) bbase[l] = a - v0;
    if (l + 64 < nblk) bbase[l + 64] = tot0 + b - v1;
    if (l == 0) offsets[N_NODES] = tot0 + tot1;   // == N_EDGES
}

// ---------------------------------------------------------------------------
// Kernel 3c: fan-out — per-node exclusive offsets + cursor
// ---------------------------------------------------------------------------
__global__ __launch_bounds__(256) void scan_fanout_kernel(
    const int* __restrict__ deg, const int* __restrict__ bbase,
    int* __restrict__ offsets, int* __restrict__ cursor)
{
    __shared__ int sc[256];
    const int t = threadIdx.x;
    const int base = blockIdx.x * 1024 + t * 4;

    int d[4] = {0, 0, 0, 0};
    if (base + 3 < N_NODES) {
        const int4 q = *reinterpret_cast<const int4*>(deg + base);
        d[0] = q.x; d[1] = q.y; d[2] = q.z; d[3] = q.w;
    } else {
        for (int k = 0; k < 4; ++k)
            if (base + k < N_NODES) d[k] = deg[base + k];
    }
    const int s = d[0] + d[1] + d[2] + d[3];
    sc[t] = s;
    __syncthreads();
    for (int off = 1; off < 256; off <<= 1) {
        const int val = sc[t];
        const int add = (t >= off) ? sc[t - off] : 0;
        __syncthreads();
        sc[t] = val + add;
        __syncthreads();
    }
    int run = bbase[blockIdx.x] + sc[t] - s;   // exclusive base for this thread
    #pragma unroll
    for (int k = 0; k < 4; ++k) {
        const int i = base + k;
        if (i < N_NODES) {
            offsets[i] = run;
            cursor[i]  = run;
            run += d[k];
        }
    }
}

// ---------------------------------------------------------------------------
// Kernel 4: XCD-binned CSR fill. bin = blockIdx%8 -> (assumed) XCD id;
// each bin owns dst range [bin*12500, +12500) whose CSR window (~1.6MB)
// stays L2-resident on that XCD. 4 atomics in flight per thread.
// ---------------------------------------------------------------------------
__global__ __launch_bounds__(256) void fill_kernel(
    const int* __restrict__ ei, int* __restrict__ cursor, int* __restrict__ csr_src)
{
    const int bin  = blockIdx.x & (NBIN - 1);
    const int slot = (blockIdx.x >> 3) * 256 + threadIdx.x;   // 0..FILL_SLOTS-1
    const int lo = bin * BIN_SIZE;
    const int hi = lo + BIN_SIZE;

    for (int e0 = slot; e0 < N_EDGES; e0 += 4 * FILL_SLOTS) {
        const int e1 = e0 + FILL_SLOTS;
        const int e2 = e0 + 2 * FILL_SLOTS;
        const int e3 = e0 + 3 * FILL_SLOTS;

        const int d0 = ei[N_EDGES + e0];
        const int s0 = ei[e0];
        const int d1 = (e1 < N_EDGES) ? ei[N_EDGES + e1] : -1;
        const int s1 = (e1 < N_EDGES) ? ei[e1] : 0;
        const int d2 = (e2 < N_EDGES) ? ei[N_EDGES + e2] : -1;
        const int s2 = (e2 < N_EDGES) ? ei[e2] : 0;
        const int d3 = (e3 < N_EDGES) ? ei[N_EDGES + e3] : -1;
        const int s3 = (e3 < N_EDGES) ? ei[e3] : 0;

        const bool m0 = (d0 >= lo) & (d0 < hi);
        const bool m1 = (d1 >= lo) & (d1 < hi);
        const bool m2 = (d2 >= lo) & (d2 < hi);
        const bool m3 = (d3 >= lo) & (d3 < hi);

        int p0 = 0, p1 = 0, p2 = 0, p3 = 0;
        if (m0) p0 = atomicAdd(&cursor[d0], 1);
        if (m1) p1 = atomicAdd(&cursor[d1], 1);
        if (m2) p2 = atomicAdd(&cursor[d2], 1);
        if (m3) p3 = atomicAdd(&cursor[d3], 1);
        if (m0) csr_src[p0] = s0;
        if (m1) csr_src[p1] = s1;
        if (m2) csr_src[p2] = s2;
        if (m3) csr_src[p3] = s3;
    }
}

// ---------------------------------------------------------------------------
// Kernel 5: gather-sum. 4 lanes/node; lane c reads uint4 (8 bf16) chunk c.
// No atomics; writes every output element.
// ---------------------------------------------------------------------------
__global__ __launch_bounds__(256) void gather_kernel(
    const int* __restrict__ offsets, const int* __restrict__ csr_src,
    const unsigned* __restrict__ y, float* __restrict__ out)
{
    const int t = blockIdx.x * 256 + threadIdx.x;
    const int v = t >> 2;
    const int c = t & 3;
    if (v >= N_NODES) return;

    const int beg = offsets[v];
    const int end = offsets[v + 1];

    float acc[8];
    #pragma unroll
    for (int k = 0; k < 8; ++k) acc[k] = 0.0f;

    int i = beg;
    for (; i + 1 < end; i += 2) {
        const int sA = csr_src[i];
        const int sB = csr_src[i + 1];
        const uint4 rA = reinterpret_cast<const uint4*>(y + (size_t)sA * 16)[c];
        const uint4 rB = reinterpret_cast<const uint4*>(y + (size_t)sB * 16)[c];
        const unsigned qa[4] = {rA.x, rA.y, rA.z, rA.w};
        const unsigned qb[4] = {rB.x, rB.y, rB.z, rB.w};
        #pragma unroll
        for (int k = 0; k < 4; ++k) {
            acc[2 * k + 0] += __uint_as_float(qa[k] << 16);
            acc[2 * k + 1] += __uint_as_float(qa[k] & 0xFFFF0000u);
            acc[2 * k + 0] += __uint_as_float(qb[k] << 16);
            acc[2 * k + 1] += __uint_as_float(qb[k] & 0xFFFF0000u);
        }
    }
    if (i < end) {
        const int sA = csr_src[i];
        const uint4 rA = reinterpret_cast<const uint4*>(y + (size_t)sA * 16)[c];
        const unsigned qa[4] = {rA.x, rA.y, rA.z, rA.w};
        #pragma unroll
        for (int k = 0; k < 4; ++k) {
            acc[2 * k + 0] += __uint_as_float(qa[k] << 16);
            acc[2 * k + 1] += __uint_as_float(qa[k] & 0xFFFF0000u);
        }
    }

    float4* op = reinterpret_cast<float4*>(out + (size_t)v * F_OUT + c * 8);
    op[0] = make_float4(acc[0], acc[1], acc[2], acc[3]);
    op[1] = make_float4(acc[4], acc[5], acc[6], acc[7]);
}

extern "C" void kernel_launch(void* const* d_in, const int* in_sizes, int n_in,
                              void* d_out, int out_size, void* d_ws, size_t ws_size,
                              hipStream_t stream) {
    const float* x       = (const float*)d_in[0];
    const float* scalars = (const float*)d_in[1];
    const int*   ei      = (const int*)d_in[2];
    const float* W1      = (const float*)d_in[3];
    const float* b1      = (const float*)d_in[4];
    const float* W2      = (const float*)d_in[5];
    const float* b2      = (const float*)d_in[6];
    float* out = (float*)d_out;

    // Workspace layout (all 64B-aligned), total 20,401,088 B
    char* ws = (char*)d_ws;
    unsigned* y   = (unsigned*)ws;                  //  6,400,000 B  [N,16] uints (bf16 pairs)
    int* deg      = (int*)(ws + 6400000);           //    400,000 B
    int* offsets  = (int*)(ws + 6800000);           //    400,004 B (N+1)
    int* cursor   = (int*)(ws + 7200064);           //    400,000 B
    int* bsum     = (int*)(ws + 7600064);           //        512 B (98 used)
    int* bbase    = (int*)(ws + 7600576);           //        512 B
    int* csr_src  = (int*)(ws + 7601088);           // 12,800,000 B

    const int nblk_scan = (N_NODES + 1023) / 1024;  // 98

    // 1) per-node MLP -> bf16 y
    node_mlp_kernel<<<(N_NODES + 255) / 256, 256, 0, stream>>>(
        x, scalars, W1, b1, W2, b2, y);

    // 2) histogram
    hipMemsetAsync(deg, 0, (size_t)N_NODES * sizeof(int), stream);
    hist_kernel<<<3125, 256, 0, stream>>>(ei, deg);

    // 3) three-level scan -> offsets, cursor
    scan_blocksum_kernel<<<nblk_scan, 256, 0, stream>>>(deg, bsum);
    scan_top_kernel<<<1, 64, 0, stream>>>(bsum, bbase, offsets, nblk_scan);
    scan_fanout_kernel<<<nblk_scan, 256, 0, stream>>>(deg, bbase, offsets, cursor);

    // 4) XCD-binned CSR fill
    fill_kernel<<<FILL_BLOCKS, 256, 0, stream>>>(ei, cursor, csr_src);

    // 5) gather-sum into output
    gather_kernel<<<(N_NODES * 4 + 255) / 256, 256, 0, stream>>>(
        offsets, csr_src, y, out);
}